// Round 1
// baseline (562.719 us; speedup 1.0000x reference)
//
#include <hip/hip_runtime.h>

typedef __attribute__((ext_vector_type(8))) short short8;
typedef __attribute__((ext_vector_type(4))) float floatx4;
typedef unsigned short u16;
typedef unsigned int u32;

#define NB 8
#define CI 512
#define CO 512
#define HH 64
#define WW 64
#define HP 66
#define WP 66

__device__ __forceinline__ u16 f2bf(float f) {
  u32 u = __builtin_bit_cast(u32, f);
  u += 0x7fffu + ((u >> 16) & 1u);
  return (u16)(u >> 16);
}

// s[b,i] = coef * dot(y[b,:], affine_w[i,:]) + affine_b[i] + 1
__global__ __launch_bounds__(256) void k_style(
    const float* __restrict__ y, const float* __restrict__ aw,
    const float* __restrict__ ab, float* __restrict__ s)
{
  const int wid = blockIdx.x * 4 + (threadIdx.x >> 6);
  const int lane = threadIdx.x & 63;
  const int b = wid >> 9, i = wid & 511;
  float sum = 0.f;
  #pragma unroll
  for (int j = 0; j < 8; ++j) {
    const int k = lane + (j << 6);
    sum += y[b * CI + k] * aw[i * CI + k];
  }
  #pragma unroll
  for (int off = 32; off; off >>= 1) sum += __shfl_xor(sum, off);
  if (lane == 0) s[wid] = sum * 0.044194173824159216f + ab[i] + 1.0f;
}

// wsum[o,i] = sum_t weight[o,i,t]^2
__global__ __launch_bounds__(256) void k_wsum(
    const float* __restrict__ wt, float* __restrict__ wsum)
{
  const int idx = blockIdx.x * 256 + threadIdx.x;   // o*512+i
  const float* p = wt + (size_t)idx * 9;
  float sum = 0.f;
  #pragma unroll
  for (int t = 0; t < 9; ++t) sum += p[t] * p[t];
  wsum[idx] = sum;
}

// wb[(o*9+t)*512+i] = bf16(weight[o,i,t])
__global__ __launch_bounds__(256) void k_wb(
    const float* __restrict__ wt, u16* __restrict__ wb)
{
  const int idx = blockIdx.x * 256 + threadIdx.x;   // (o*9+t)*512+i
  const int i = idx & 511;
  const int ot = idx >> 9;
  const int t = ot % 9;
  const int o = ot / 9;
  wb[idx] = f2bf(wt[((size_t)o * CI + i) * 9 + t]);
}

// d[b,o] = rsqrt(sum_i wsum[o,i]*s[b,i]^2 + 1e-4)
__global__ __launch_bounds__(256) void k_demod(
    const float* __restrict__ wsum, const float* __restrict__ s,
    float* __restrict__ d)
{
  const int wid = blockIdx.x * 4 + (threadIdx.x >> 6);
  const int lane = threadIdx.x & 63;
  const int b = wid >> 9, o = wid & 511;
  float sum = 0.f;
  #pragma unroll
  for (int j = 0; j < 8; ++j) {
    const int i = lane + (j << 6);
    const float sv = s[b * CI + i];
    sum += wsum[o * CI + i] * sv * sv;
  }
  #pragma unroll
  for (int off = 32; off; off >>= 1) sum += __shfl_xor(sum, off);
  if (lane == 0) d[wid] = rsqrtf(sum + 1e-4f);
}

// xs[b, h+1, w+1, i] (NHWC, 66x66 padded, bf16) = x[b,i,h,w] * s[b,i]
// block: (b, h, i-chunk of 64); transpose via LDS
__global__ __launch_bounds__(256) void k_xform(
    const float* __restrict__ x, const float* __restrict__ s,
    u16* __restrict__ xs)
{
  __shared__ __align__(16) u16 lds[64 * 72];
  const int blk = blockIdx.x;          // ((b*64+h)*8 + ic)
  const int ic = blk & 7;
  const int h = (blk >> 3) & 63;
  const int b = blk >> 9;
  const int i0 = ic << 6;
  const int t = threadIdx.x;
  const int w = t & 63;
  const int i4 = t >> 6;
  #pragma unroll
  for (int p = 0; p < 16; ++p) {
    const int ii = i4 + (p << 2);
    const float xv = x[((size_t)(b * CI + i0 + ii) * HH + h) * WW + w];
    const float sv = s[b * CI + i0 + ii];
    lds[w * 72 + ii] = f2bf(xv * sv);
  }
  __syncthreads();
  const int w2 = t >> 2;
  const int q = t & 3;
  const uint4* src = (const uint4*)&lds[w2 * 72 + (q << 4)];
  const uint4 v0 = src[0];
  const uint4 v1 = src[1];
  u16* dst = xs + ((size_t)(b * HP + h + 1) * WP + (w2 + 1)) * CI + i0 + (q << 4);
  *(uint4*)dst = v0;
  *((uint4*)dst + 1) = v1;
}

// implicit-GEMM conv: block = 64 O x (4 rows x 64 w) for one sample.
// 4 waves, wave = one output row. MFMA 16x16x32 bf16.
__global__ __launch_bounds__(256) void k_conv(
    const u16* __restrict__ xs, const u16* __restrict__ wb,
    const float* __restrict__ dmod, const float* __restrict__ bias,
    float* __restrict__ out)
{
  const int blk = blockIdx.x;
  const int b = blk >> 7;
  const int ot = (blk >> 4) & 7;
  const int ht = blk & 15;
  const int wave = threadIdx.x >> 6;
  const int lane = threadIdx.x & 63;
  const int col = lane & 15;
  const int k8 = lane >> 4;
  const int h = ht * 4 + wave;         // output row owned by this wave
  const int ob = ot * 64;

  floatx4 acc[4][4];
  #pragma unroll
  for (int m = 0; m < 4; ++m)
    #pragma unroll
    for (int n = 0; n < 4; ++n)
      acc[m][n] = (floatx4){0.f, 0.f, 0.f, 0.f};

  for (int tap = 0; tap < 9; ++tap) {
    const int kh = tap / 3;
    const int kw = tap - kh * 3;
    const u16* ap[4];
    const u16* bp[4];
    #pragma unroll
    for (int m = 0; m < 4; ++m)
      ap[m] = wb + (((ob + m * 16 + col) * 9 + tap) << 9) + (k8 << 3);
    #pragma unroll
    for (int n = 0; n < 4; ++n)
      bp[n] = xs + (((b * HP + h + kh) * WP + (n * 16 + col + kw)) << 9) + (k8 << 3);
    #pragma unroll 2
    for (int i0 = 0; i0 < 512; i0 += 32) {
      short8 av[4], bv[4];
      #pragma unroll
      for (int m = 0; m < 4; ++m) av[m] = *(const short8*)(ap[m] + i0);
      #pragma unroll
      for (int n = 0; n < 4; ++n) bv[n] = *(const short8*)(bp[n] + i0);
      #pragma unroll
      for (int n = 0; n < 4; ++n)
        #pragma unroll
        for (int m = 0; m < 4; ++m)
          acc[m][n] = __builtin_amdgcn_mfma_f32_16x16x32_bf16(av[m], bv[n], acc[m][n], 0, 0, 0);
    }
  }

  // epilogue: out = acc * d[b,o] + bias[o]   (C/D: col=lane&15, row=(lane>>4)*4+r)
  #pragma unroll
  for (int m = 0; m < 4; ++m) {
    #pragma unroll
    for (int r = 0; r < 4; ++r) {
      const int o = ob + m * 16 + k8 * 4 + r;
      const float dm = dmod[b * CO + o];
      const float bs = bias[o];
      #pragma unroll
      for (int n = 0; n < 4; ++n) {
        const int w = n * 16 + col;
        out[(((size_t)b * CO + o) * HH + h) * WW + w] = acc[m][n][r] * dm + bs;
      }
    }
  }
}

extern "C" void kernel_launch(void* const* d_in, const int* in_sizes, int n_in,
                              void* d_out, int out_size, void* d_ws, size_t ws_size,
                              hipStream_t stream) {
  const float* x    = (const float*)d_in[0];
  const float* y    = (const float*)d_in[1];
  const float* aw   = (const float*)d_in[2];
  const float* ab   = (const float*)d_in[3];
  const float* wt   = (const float*)d_in[4];
  const float* bias = (const float*)d_in[5];
  float* out = (float*)d_out;

  // workspace layout (needs ~41.5 MB)
  char* ws = (char*)d_ws;
  const size_t XS_BYTES = (size_t)NB * HP * WP * CI * 2;     // 35,684,352
  const size_t WB_BYTES = (size_t)CO * 9 * CI * 2;           //  4,718,592
  const size_t WS_BYTES = (size_t)CO * CI * 4;               //  1,048,576
  u16* xs     = (u16*)ws;
  u16* wbuf   = (u16*)(ws + XS_BYTES);
  float* wsum = (float*)(ws + XS_BYTES + WB_BYTES);
  float* sbuf = (float*)(ws + XS_BYTES + WB_BYTES + WS_BYTES);
  float* dbuf = sbuf + NB * CI;

  hipMemsetAsync(xs, 0, XS_BYTES, stream);                   // zero halo border
  k_style<<<dim3(1024), dim3(256), 0, stream>>>(y, aw, ab, sbuf);
  k_wsum <<<dim3(1024), dim3(256), 0, stream>>>(wt, wsum);
  k_wb   <<<dim3(9216), dim3(256), 0, stream>>>(wt, wbuf);
  k_demod<<<dim3(1024), dim3(256), 0, stream>>>(wsum, sbuf, dbuf);
  k_xform<<<dim3(4096), dim3(256), 0, stream>>>(x, sbuf, xs);
  k_conv <<<dim3(1024), dim3(256), 0, stream>>>(xs, wbuf, dbuf, bias, out);
}

// Round 2
// 239.622 us; speedup vs baseline: 2.3484x; 2.3484x over previous
//
#include <hip/hip_runtime.h>

typedef __attribute__((ext_vector_type(8))) short short8;
typedef __attribute__((ext_vector_type(4))) float floatx4;
typedef unsigned short u16;
typedef unsigned int u32;

#define NB 8
#define CI 512
#define CO 512
#define HH 64
#define WW 64
#define HP 66
#define WP 66
#define BK 64

__device__ __forceinline__ u16 f2bf(float f) {
  u32 u = __builtin_bit_cast(u32, f);
  u += 0x7fffu + ((u >> 16) & 1u);
  return (u16)(u >> 16);
}

__device__ __forceinline__ void gload16(const void* g, void* l) {
  __builtin_amdgcn_global_load_lds(
      (const __attribute__((address_space(1))) unsigned int*)g,
      (__attribute__((address_space(3))) unsigned int*)l, 16, 0, 0);
}

// s[b,i] = coef * dot(y[b,:], affine_w[i,:]) + affine_b[i] + 1
__global__ __launch_bounds__(256) void k_style(
    const float* __restrict__ y, const float* __restrict__ aw,
    const float* __restrict__ ab, float* __restrict__ s)
{
  const int wid = blockIdx.x * 4 + (threadIdx.x >> 6);
  const int lane = threadIdx.x & 63;
  const int b = wid >> 9, i = wid & 511;
  float sum = 0.f;
  #pragma unroll
  for (int j = 0; j < 8; ++j) {
    const int k = lane + (j << 6);
    sum += y[b * CI + k] * aw[i * CI + k];
  }
  #pragma unroll
  for (int off = 32; off; off >>= 1) sum += __shfl_xor(sum, off);
  if (lane == 0) s[wid] = sum * 0.044194173824159216f + ab[i] + 1.0f;
}

// wsum[o,i] = sum_t weight[o,i,t]^2
__global__ __launch_bounds__(256) void k_wsum(
    const float* __restrict__ wt, float* __restrict__ wsum)
{
  const int idx = blockIdx.x * 256 + threadIdx.x;   // o*512+i
  const float* p = wt + (size_t)idx * 9;
  float sum = 0.f;
  #pragma unroll
  for (int t = 0; t < 9; ++t) sum += p[t] * p[t];
  wsum[idx] = sum;
}

// wb[(o*9+t)*512+i] = bf16(weight[o,i,t])
__global__ __launch_bounds__(256) void k_wb(
    const float* __restrict__ wt, u16* __restrict__ wb)
{
  const int idx = blockIdx.x * 256 + threadIdx.x;   // (o*9+t)*512+i
  const int i = idx & 511;
  const int ot = idx >> 9;
  const int t = ot % 9;
  const int o = ot / 9;
  wb[idx] = f2bf(wt[((size_t)o * CI + i) * 9 + t]);
}

// d[b,o] = rsqrt(sum_i wsum[o,i]*s[b,i]^2 + 1e-4)
__global__ __launch_bounds__(256) void k_demod(
    const float* __restrict__ wsum, const float* __restrict__ s,
    float* __restrict__ d)
{
  const int wid = blockIdx.x * 4 + (threadIdx.x >> 6);
  const int lane = threadIdx.x & 63;
  const int b = wid >> 9, o = wid & 511;
  float sum = 0.f;
  #pragma unroll
  for (int j = 0; j < 8; ++j) {
    const int i = lane + (j << 6);
    const float sv = s[b * CI + i];
    sum += wsum[o * CI + i] * sv * sv;
  }
  #pragma unroll
  for (int off = 32; off; off >>= 1) sum += __shfl_xor(sum, off);
  if (lane == 0) d[wid] = rsqrtf(sum + 1e-4f);
}

// xs[b, h+1, w+1, i] (NHWC, 66x66 padded, bf16) = x[b,i,h,w] * s[b,i]
__global__ __launch_bounds__(256) void k_xform(
    const float* __restrict__ x, const float* __restrict__ s,
    u16* __restrict__ xs)
{
  __shared__ __align__(16) u16 lds[64 * 72];
  const int blk = blockIdx.x;          // ((b*64+h)*8 + ic)
  const int ic = blk & 7;
  const int h = (blk >> 3) & 63;
  const int b = blk >> 9;
  const int i0 = ic << 6;
  const int t = threadIdx.x;
  const int w = t & 63;
  const int i4 = t >> 6;
  #pragma unroll
  for (int p = 0; p < 16; ++p) {
    const int ii = i4 + (p << 2);
    const float xv = x[((size_t)(b * CI + i0 + ii) * HH + h) * WW + w];
    const float sv = s[b * CI + i0 + ii];
    lds[w * 72 + ii] = f2bf(xv * sv);
  }
  __syncthreads();
  const int w2 = t >> 2;
  const int q = t & 3;
  const uint4* src = (const uint4*)&lds[w2 * 72 + (q << 4)];
  const uint4 v0 = src[0];
  const uint4 v1 = src[1];
  u16* dst = xs + ((size_t)(b * HP + h + 1) * WP + (w2 + 1)) * CI + i0 + (q << 4);
  *(uint4*)dst = v0;
  *((uint4*)dst + 1) = v1;
}

// implicit-GEMM conv, m97 structure: 128(O) x 128(pixels=2 rows) tile,
// BK=64, global_load_lds(16B) -> LDS -> ds_read_b128 -> MFMA 16x16x32 bf16.
// 4 waves in 2x2, each wave owns a 64x64 sub-tile.
__global__ __launch_bounds__(256) void k_conv(
    const u16* __restrict__ xs, const u16* __restrict__ wb,
    const float* __restrict__ dmod, const float* __restrict__ bias,
    float* __restrict__ out)
{
  __shared__ __align__(16) u16 lA[128 * BK];   // [m][k]  16 KB
  __shared__ __align__(16) u16 lB[128 * BK];   // [n][k]  16 KB

  const int blk = blockIdx.x;
  const int nt = blk & 31;            // h-pair tile
  const int mt = (blk >> 5) & 3;      // O tile
  const int b  = blk >> 7;            // sample
  const int h0 = nt * 2;
  const int ob = mt * 128;

  const int tid  = threadIdx.x;
  const int wid  = tid >> 6;
  const int lane = tid & 63;
  const int col  = lane & 15;
  const int k8   = lane >> 4;
  const int wr   = wid >> 1;          // wave row (O)
  const int wc   = wid & 1;           // wave col (pixels)

  // staging lane geometry: each gload16 inst stages 8 rows x 64 k (1 KB)
  const int lrow = lane >> 3;          // row within 8-row group
  const int lk   = (lane & 7) << 3;    // k element offset

  u32 aoff[4], boff[4];
  #pragma unroll
  for (int j = 0; j < 4; ++j) {
    const int r0 = (wid << 5) + (j << 3);
    aoff[j] = (u32)((((ob + r0 + lrow) * 9) << 9) + lk);
    const int p = r0 + lrow;                           // pixel index 0..127
    boff[j] = (u32)((((b * HP + h0 + (p >> 6)) * WP + (p & 63)) << 9) + lk);
  }

  floatx4 acc[4][4];
  #pragma unroll
  for (int m = 0; m < 4; ++m)
    #pragma unroll
    for (int n = 0; n < 4; ++n)
      acc[m][n] = (floatx4){0.f, 0.f, 0.f, 0.f};

  int kc = 0;
  for (int kh = 0; kh < 3; ++kh) {
    for (int kw = 0; kw < 3; ++kw) {
      const u32 tapoff = (u32)((kh * WP + kw) << 9);
      for (int i0 = 0; i0 < CI; i0 += BK, ++kc) {
        // stage 32 KB: 8 gload16 per wave
        const u32 ak = (u32)(kc << 6);
        #pragma unroll
        for (int j = 0; j < 4; ++j) {
          const int r0 = (wid << 5) + (j << 3);
          gload16(wb + aoff[j] + ak, &lA[r0 << 6]);
          gload16(xs + boff[j] + tapoff + (u32)i0, &lB[r0 << 6]);
        }
        __syncthreads();
        #pragma unroll
        for (int kk = 0; kk < 2; ++kk) {
          short8 av[4], bv[4];
          #pragma unroll
          for (int m = 0; m < 4; ++m)
            av[m] = *(const short8*)&lA[((wr << 6) + (m << 4) + col) * BK + (kk << 5) + (k8 << 3)];
          #pragma unroll
          for (int n = 0; n < 4; ++n)
            bv[n] = *(const short8*)&lB[((wc << 6) + (n << 4) + col) * BK + (kk << 5) + (k8 << 3)];
          #pragma unroll
          for (int n = 0; n < 4; ++n)
            #pragma unroll
            for (int m = 0; m < 4; ++m)
              acc[m][n] = __builtin_amdgcn_mfma_f32_16x16x32_bf16(av[m], bv[n], acc[m][n], 0, 0, 0);
        }
        __syncthreads();
      }
    }
  }

  // epilogue: out = acc * d[b,o] + bias[o]; C/D: col=lane&15, row=(lane>>4)*4+r
  const int h = h0 + wc;
  #pragma unroll
  for (int m = 0; m < 4; ++m) {
    #pragma unroll
    for (int r = 0; r < 4; ++r) {
      const int o = ob + (wr << 6) + (m << 4) + (k8 << 2) + r;
      const float dm = dmod[b * CO + o];
      const float bs = bias[o];
      float* po = out + ((size_t)(b * CO + o) * HH + h) * WW;
      #pragma unroll
      for (int n = 0; n < 4; ++n)
        po[(n << 4) + col] = acc[m][n][r] * dm + bs;
    }
  }
}

extern "C" void kernel_launch(void* const* d_in, const int* in_sizes, int n_in,
                              void* d_out, int out_size, void* d_ws, size_t ws_size,
                              hipStream_t stream) {
  const float* x    = (const float*)d_in[0];
  const float* y    = (const float*)d_in[1];
  const float* aw   = (const float*)d_in[2];
  const float* ab   = (const float*)d_in[3];
  const float* wt   = (const float*)d_in[4];
  const float* bias = (const float*)d_in[5];
  float* out = (float*)d_out;

  char* ws = (char*)d_ws;
  const size_t XS_BYTES = (size_t)NB * HP * WP * CI * 2;     // 35,684,352
  const size_t WB_BYTES = (size_t)CO * 9 * CI * 2;           //  4,718,592
  const size_t WS_BYTES = (size_t)CO * CI * 4;               //  1,048,576
  u16* xsb    = (u16*)ws;
  u16* wbuf   = (u16*)(ws + XS_BYTES);
  float* wsum = (float*)(ws + XS_BYTES + WB_BYTES);
  float* sbuf = (float*)(ws + XS_BYTES + WB_BYTES + WS_BYTES);
  float* dbuf = sbuf + NB * CI;

  hipMemsetAsync(xsb, 0, XS_BYTES, stream);                  // zero halo border
  k_style<<<dim3(1024), dim3(256), 0, stream>>>(y, aw, ab, sbuf);
  k_wsum <<<dim3(1024), dim3(256), 0, stream>>>(wt, wsum);
  k_wb   <<<dim3(9216), dim3(256), 0, stream>>>(wt, wbuf);
  k_demod<<<dim3(1024), dim3(256), 0, stream>>>(wsum, sbuf, dbuf);
  k_xform<<<dim3(4096), dim3(256), 0, stream>>>(x, sbuf, xsb);
  k_conv <<<dim3(1024), dim3(256), 0, stream>>>(xsb, wbuf, dbuf, bias, out);
}

// Round 3
// 193.021 us; speedup vs baseline: 2.9153x; 1.2414x over previous
//
#include <hip/hip_runtime.h>

typedef __attribute__((ext_vector_type(8))) short short8;
typedef __attribute__((ext_vector_type(4))) float floatx4;
typedef unsigned short u16;
typedef unsigned int u32;

#define NB 8
#define CI 512
#define CO 512
#define HH 64
#define WW 64
#define HP 66
#define WP 66
#define BK 64

__device__ __forceinline__ u16 f2bf(float f) {
  u32 u = __builtin_bit_cast(u32, f);
  u += 0x7fffu + ((u >> 16) & 1u);
  return (u16)(u >> 16);
}

__device__ __forceinline__ void gload16(const void* g, void* l) {
  __builtin_amdgcn_global_load_lds(
      (const __attribute__((address_space(1))) unsigned int*)g,
      (__attribute__((address_space(3))) unsigned int*)l, 16, 0, 0);
}

// s[b,i] = coef * dot(y[b,:], affine_w[i,:]) + affine_b[i] + 1
__global__ __launch_bounds__(256) void k_style(
    const float* __restrict__ y, const float* __restrict__ aw,
    const float* __restrict__ ab, float* __restrict__ s)
{
  const int wid = blockIdx.x * 4 + (threadIdx.x >> 6);
  const int lane = threadIdx.x & 63;
  const int b = wid >> 9, i = wid & 511;
  float sum = 0.f;
  #pragma unroll
  for (int j = 0; j < 8; ++j) {
    const int k = lane + (j << 6);
    sum += y[b * CI + k] * aw[i * CI + k];
  }
  #pragma unroll
  for (int off = 32; off; off >>= 1) sum += __shfl_xor(sum, off);
  if (lane == 0) s[wid] = sum * 0.044194173824159216f + ab[i] + 1.0f;
}

// wsum[o,i] = sum_t weight[o,i,t]^2
__global__ __launch_bounds__(256) void k_wsum(
    const float* __restrict__ wt, float* __restrict__ wsum)
{
  const int idx = blockIdx.x * 256 + threadIdx.x;   // o*512+i
  const float* p = wt + (size_t)idx * 9;
  float sum = 0.f;
  #pragma unroll
  for (int t = 0; t < 9; ++t) sum += p[t] * p[t];
  wsum[idx] = sum;
}

// wb[(o*9+t)*512+i] = bf16(weight[o,i,t])  -> A is row-major [512][4608]
__global__ __launch_bounds__(256) void k_wb(
    const float* __restrict__ wt, u16* __restrict__ wb)
{
  const int idx = blockIdx.x * 256 + threadIdx.x;   // (o*9+t)*512+i
  const int i = idx & 511;
  const int ot = idx >> 9;
  const int t = ot % 9;
  const int o = ot / 9;
  wb[idx] = f2bf(wt[((size_t)o * CI + i) * 9 + t]);
}

// d[b,o] = rsqrt(sum_i wsum[o,i]*s[b,i]^2 + 1e-4)
__global__ __launch_bounds__(256) void k_demod(
    const float* __restrict__ wsum, const float* __restrict__ s,
    float* __restrict__ d)
{
  const int wid = blockIdx.x * 4 + (threadIdx.x >> 6);
  const int lane = threadIdx.x & 63;
  const int b = wid >> 9, o = wid & 511;
  float sum = 0.f;
  #pragma unroll
  for (int j = 0; j < 8; ++j) {
    const int i = lane + (j << 6);
    const float sv = s[b * CI + i];
    sum += wsum[o * CI + i] * sv * sv;
  }
  #pragma unroll
  for (int off = 32; off; off >>= 1) sum += __shfl_xor(sum, off);
  if (lane == 0) d[wid] = rsqrtf(sum + 1e-4f);
}

// xs[b, h+1, w+1, i] (NHWC, 66x66 padded, bf16) = x[b,i,h,w] * s[b,i]
__global__ __launch_bounds__(256) void k_xform(
    const float* __restrict__ x, const float* __restrict__ s,
    u16* __restrict__ xs)
{
  __shared__ __align__(16) u16 lds[64 * 72];
  const int blk = blockIdx.x;          // ((b*64+h)*8 + ic)
  const int ic = blk & 7;
  const int h = (blk >> 3) & 63;
  const int b = blk >> 9;
  const int i0 = ic << 6;
  const int t = threadIdx.x;
  const int w = t & 63;
  const int i4 = t >> 6;
  #pragma unroll
  for (int p = 0; p < 16; ++p) {
    const int ii = i4 + (p << 2);
    const float xv = x[((size_t)(b * CI + i0 + ii) * HH + h) * WW + w];
    const float sv = s[b * CI + i0 + ii];
    lds[w * 72 + ii] = f2bf(xv * sv);
  }
  __syncthreads();
  const int w2 = t >> 2;
  const int q = t & 3;
  const uint4* src = (const uint4*)&lds[w2 * 72 + (q << 4)];
  const uint4 v0 = src[0];
  const uint4 v1 = src[1];
  u16* dst = xs + ((size_t)(b * HP + h + 1) * WP + (w2 + 1)) * CI + i0 + (q << 4);
  *(uint4*)dst = v0;
  *((uint4*)dst + 1) = v1;
}

// ---------------------------------------------------------------------------
// implicit-GEMM conv, 256x256 deep-pipelined template (T2+T3+T4+T5):
// BM=256 (O), BN=256 (pixels = 4 rows x 64 w), BK=64, K = 9 taps x 512 = 72 tiles.
// 512 threads, 8 waves (2M x 4N), per-wave C = 128x64 (8m x 4n frags).
// LDS 128 KB: double-buffered A[256][64] + B[256][64] bf16, XOR slot swizzle.
// Pipeline: tile t+2 staged (8 gload16/wave) after t's last ds_read;
// s_waitcnt vmcnt(8) at tile end -> tile t+1 complete, t+2 in flight.
// ---------------------------------------------------------------------------
__global__ __launch_bounds__(512, 2) void k_conv(
    const u16* __restrict__ xs, const u16* __restrict__ wb,
    const float* __restrict__ dmod, const float* __restrict__ bias,
    float* __restrict__ out)
{
  __shared__ __align__(16) u16 lA[2 * 16384];
  __shared__ __align__(16) u16 lB[2 * 16384];

  const int blk = blockIdx.x;
  const int nt = blk & 15;
  const int mt = (blk >> 4) & 1;
  const int b  = blk >> 5;
  const int ob = mt << 8;
  const int p0 = nt << 8;

  const int tid = threadIdx.x;
  const int wid = tid >> 6;
  const int lane = tid & 63;
  const int col = lane & 15;
  const int k8  = lane >> 4;
  const int wr  = wid >> 2;          // wave M index (0..1)
  const int wc  = wid & 3;           // wave N index (0..3)

  // staging lane geometry: gload16 stages 8 rows x 8 slots (1 KB), LDS linear.
  // source column pre-swizzled: lane l fetches slot (l&7)^(l>>3) of its row.
  const int lr = lane >> 3;
  const int ls = lane & 7;
  const int swz = ls ^ lr;

  u32 aoffs[4], boffs[4], ldst[4];
  #pragma unroll
  for (int g = 0; g < 4; ++g) {
    const int rg = (wid << 5) + (g << 3);        // row-group base 0..255
    aoffs[g] = (u32)((ob + rg + lr) * 4608 + (swz << 3));
    const int p = p0 + rg + lr;
    boffs[g] = (u32)(((b * HP + (p >> 6)) * WP + (p & 63)) * 512 + (swz << 3));
    ldst[g] = (u32)(rg << 6);
  }

  // ds_read swizzled slot offsets (elements): slot (kk*4+k8) ^ (row&7), row&7 == col&7
  const u32 sA0 = (u32)(((0 + k8) ^ (col & 7)) << 3);
  const u32 sA1 = (u32)(((4 + k8) ^ (col & 7)) << 3);
  const u32 aRead = (u32)((((wr << 7) + col) << 6));
  const u32 bRead = (u32)((((wc << 6) + col) << 6));

  floatx4 acc[8][4];
  #pragma unroll
  for (int m = 0; m < 8; ++m)
    #pragma unroll
    for (int n = 0; n < 4; ++n)
      acc[m][n] = (floatx4){0.f, 0.f, 0.f, 0.f};

  short8 a0[4][2], b0[2][2], b1[2][2];

#define STAGE(KC, C) do {                                                     \
    const int tap_ = (KC) >> 3;                                               \
    const int kh_ = tap_ / 3;                                                 \
    const int kw_ = tap_ - kh_ * 3;                                           \
    const u32 at_ = (u32)((KC) << 6);                                         \
    const u32 bt_ = (u32)(((kh_ * WP + kw_) << 9) + (((KC) & 7) << 6));       \
    _Pragma("unroll")                                                         \
    for (int g = 0; g < 4; ++g) {                                             \
      gload16(wb + aoffs[g] + at_, &lA[((C) << 14) + ldst[g]]);               \
      gload16(xs + boffs[g] + bt_, &lB[((C) << 14) + ldst[g]]);               \
    }                                                                         \
  } while (0)

#define READ_A(PA, MH) do {                                                   \
    _Pragma("unroll")                                                         \
    for (int mq = 0; mq < 4; ++mq) {                                          \
      a0[mq][0] = *(const short8*)((PA) + (MH) * 4096 + mq * 1024 + sA0);     \
      a0[mq][1] = *(const short8*)((PA) + (MH) * 4096 + mq * 1024 + sA1);     \
    }                                                                         \
  } while (0)

#define READ_B(PB, NH, BV) do {                                               \
    _Pragma("unroll")                                                         \
    for (int nq = 0; nq < 2; ++nq) {                                          \
      BV[nq][0] = *(const short8*)((PB) + (NH) * 2048 + nq * 1024 + sA0);     \
      BV[nq][1] = *(const short8*)((PB) + (NH) * 2048 + nq * 1024 + sA1);     \
    }                                                                         \
  } while (0)

#define MFMA_Q(MH, NH, BV) do {                                               \
    _Pragma("unroll")                                                         \
    for (int kk = 0; kk < 2; ++kk)                                            \
      _Pragma("unroll")                                                       \
      for (int nq = 0; nq < 2; ++nq)                                          \
        _Pragma("unroll")                                                     \
        for (int mq = 0; mq < 4; ++mq)                                        \
          acc[(MH)*4+mq][(NH)*2+nq] = __builtin_amdgcn_mfma_f32_16x16x32_bf16(\
              a0[mq][kk], BV[nq][kk], acc[(MH)*4+mq][(NH)*2+nq], 0, 0, 0);    \
  } while (0)

#define BODY(T, DOSTAGE, WMODE) do {                                          \
    const int c_ = (T) & 1;                                                   \
    const u16* pA = lA + (c_ << 14) + aRead;                                  \
    const u16* pB = lB + (c_ << 14) + bRead;                                  \
    READ_A(pA, 0);                                                            \
    READ_B(pB, 0, b0);                                                        \
    __builtin_amdgcn_s_barrier();                                             \
    __builtin_amdgcn_s_setprio(1); MFMA_Q(0, 0, b0); __builtin_amdgcn_s_setprio(0); \
    __builtin_amdgcn_s_barrier();                                             \
    READ_B(pB, 1, b1);                                                        \
    __builtin_amdgcn_s_barrier();                                             \
    __builtin_amdgcn_s_setprio(1); MFMA_Q(0, 1, b1); __builtin_amdgcn_s_setprio(0); \
    __builtin_amdgcn_s_barrier();                                             \
    READ_A(pA, 1);                                                            \
    __builtin_amdgcn_s_barrier();                                             \
    __builtin_amdgcn_s_setprio(1); MFMA_Q(1, 1, b1); __builtin_amdgcn_s_setprio(0); \
    __builtin_amdgcn_s_barrier();                                             \
    __builtin_amdgcn_sched_barrier(0);                                        \
    if (DOSTAGE) STAGE((T) + 2, c_);                                          \
    __builtin_amdgcn_sched_barrier(0);                                        \
    __builtin_amdgcn_s_setprio(1); MFMA_Q(1, 0, b0); __builtin_amdgcn_s_setprio(0); \
    if (WMODE == 1)      asm volatile("s_waitcnt vmcnt(8)" ::: "memory");     \
    else if (WMODE == 2) asm volatile("s_waitcnt vmcnt(0)" ::: "memory");     \
    __builtin_amdgcn_sched_barrier(0);                                        \
    if (WMODE != 0) __builtin_amdgcn_s_barrier();                             \
  } while (0)

  // prologue: stage tiles 0 and 1, wait for tile 0 (8 newer stay in flight)
  STAGE(0, 0);
  STAGE(1, 1);
  asm volatile("s_waitcnt vmcnt(8)" ::: "memory");
  __builtin_amdgcn_sched_barrier(0);
  __builtin_amdgcn_s_barrier();

  for (int t = 0; t < 70; ++t) BODY(t, 1, 1);
  BODY(70, 0, 2);
  BODY(71, 0, 0);

#undef STAGE
#undef READ_A
#undef READ_B
#undef MFMA_Q
#undef BODY

  // epilogue: out = acc * d[b,o] + bias[o]; C/D: col=lane&15, row=(lane>>4)*4+r
  #pragma unroll
  for (int m = 0; m < 8; ++m) {
    #pragma unroll
    for (int r = 0; r < 4; ++r) {
      const int o = ob + (wr << 7) + (m << 4) + (k8 << 2) + r;
      const float dm = dmod[b * CO + o];
      const float bs = bias[o];
      float* po = out + (((size_t)(b * CO + o)) << 12) + p0 + (wc << 6);
      #pragma unroll
      for (int n = 0; n < 4; ++n)
        po[(n << 4) + col] = acc[m][n][r] * dm + bs;
    }
  }
}

extern "C" void kernel_launch(void* const* d_in, const int* in_sizes, int n_in,
                              void* d_out, int out_size, void* d_ws, size_t ws_size,
                              hipStream_t stream) {
  const float* x    = (const float*)d_in[0];
  const float* y    = (const float*)d_in[1];
  const float* aw   = (const float*)d_in[2];
  const float* ab   = (const float*)d_in[3];
  const float* wt   = (const float*)d_in[4];
  const float* bias = (const float*)d_in[5];
  float* out = (float*)d_out;

  char* ws = (char*)d_ws;
  const size_t XS_BYTES = (size_t)NB * HP * WP * CI * 2;     // 35,684,352
  const size_t WB_BYTES = (size_t)CO * 9 * CI * 2;           //  4,718,592
  const size_t WS_BYTES = (size_t)CO * CI * 4;               //  1,048,576
  u16* xsb    = (u16*)ws;
  u16* wbuf   = (u16*)(ws + XS_BYTES);
  float* wsum = (float*)(ws + XS_BYTES + WB_BYTES);
  float* sbuf = (float*)(ws + XS_BYTES + WB_BYTES + WS_BYTES);
  float* dbuf = sbuf + NB * CI;

  hipMemsetAsync(xsb, 0, XS_BYTES, stream);                  // zero halo border
  k_style<<<dim3(1024), dim3(256), 0, stream>>>(y, aw, ab, sbuf);
  k_wsum <<<dim3(1024), dim3(256), 0, stream>>>(wt, wsum);
  k_wb   <<<dim3(9216), dim3(256), 0, stream>>>(wt, wbuf);
  k_demod<<<dim3(1024), dim3(256), 0, stream>>>(wsum, sbuf, dbuf);
  k_xform<<<dim3(4096), dim3(256), 0, stream>>>(x, sbuf, xsb);
  k_conv <<<dim3(256), dim3(512), 0, stream>>>(xsb, wbuf, dbuf, bias, out);
}

// Round 4
// 164.918 us; speedup vs baseline: 3.4121x; 1.1704x over previous
//
#include <hip/hip_runtime.h>

typedef __attribute__((ext_vector_type(8))) short short8;
typedef __attribute__((ext_vector_type(4))) float floatx4;
typedef unsigned short u16;
typedef unsigned int u32;

#define NB 8
#define CI 512
#define CO 512
#define HH 64
#define WW 64
#define HP 66
#define WP 66
#define BK 64

__device__ __forceinline__ u16 f2bf(float f) {
  u32 u = __builtin_bit_cast(u32, f);
  u += 0x7fffu + ((u >> 16) & 1u);
  return (u16)(u >> 16);
}

__device__ __forceinline__ void gload16(const void* g, void* l) {
  __builtin_amdgcn_global_load_lds(
      (const __attribute__((address_space(1))) unsigned int*)g,
      (__attribute__((address_space(3))) unsigned int*)l, 16, 0, 0);
}

// s[b,i] = coef * dot(y[b,:], affine_w[i,:]) + affine_b[i] + 1
__global__ __launch_bounds__(256) void k_style(
    const float* __restrict__ y, const float* __restrict__ aw,
    const float* __restrict__ ab, float* __restrict__ s)
{
  const int wid = blockIdx.x * 4 + (threadIdx.x >> 6);
  const int lane = threadIdx.x & 63;
  const int b = wid >> 9, i = wid & 511;
  float sum = 0.f;
  #pragma unroll
  for (int j = 0; j < 8; ++j) {
    const int k = lane + (j << 6);
    sum += y[b * CI + k] * aw[i * CI + k];
  }
  #pragma unroll
  for (int off = 32; off; off >>= 1) sum += __shfl_xor(sum, off);
  if (lane == 0) s[wid] = sum * 0.044194173824159216f + ab[i] + 1.0f;
}

// fused: wsum[o,i] = sum_t weight[o,i,t]^2 ; wb[(o*9+t)*512+i] = bf16(weight[o,i,t])
__global__ __launch_bounds__(256) void k_wprep(
    const float* __restrict__ wt, float* __restrict__ wsum, u16* __restrict__ wbv)
{
  const int idx = blockIdx.x * 256 + threadIdx.x;   // o*512+i
  const int i = idx & 511;
  const int o = idx >> 9;
  const float* p = wt + (size_t)idx * 9;
  float v[9];
  float sum = 0.f;
  #pragma unroll
  for (int t = 0; t < 9; ++t) { v[t] = p[t]; sum += v[t] * v[t]; }
  wsum[idx] = sum;
  #pragma unroll
  for (int t = 0; t < 9; ++t) wbv[(((o * 9 + t) << 9) | i)] = f2bf(v[t]);
}

// d[b,o] = rsqrt(sum_i wsum[o,i]*s[b,i]^2 + 1e-4)
__global__ __launch_bounds__(256) void k_demod(
    const float* __restrict__ wsum, const float* __restrict__ s,
    float* __restrict__ d)
{
  const int wid = blockIdx.x * 4 + (threadIdx.x >> 6);
  const int lane = threadIdx.x & 63;
  const int b = wid >> 9, o = wid & 511;
  float sum = 0.f;
  #pragma unroll
  for (int j = 0; j < 8; ++j) {
    const int i = lane + (j << 6);
    const float sv = s[b * CI + i];
    sum += wsum[o * CI + i] * sv * sv;
  }
  #pragma unroll
  for (int off = 32; off; off >>= 1) sum += __shfl_xor(sum, off);
  if (lane == 0) d[wid] = rsqrtf(sum + 1e-4f);
}

// xs[b, h+1, w+1, i] (NHWC, 66x66 padded, bf16) = x[b,i,h,w] * s[b,i]
// also zeroes its own slice of the halo border (replaces the 35 MB memset).
__global__ __launch_bounds__(256) void k_xform(
    const float* __restrict__ x, const float* __restrict__ s,
    u16* __restrict__ xs)
{
  __shared__ __align__(16) u16 lds[64 * 72];
  const int blk = blockIdx.x;          // ((b*64+h)*8 + ic)
  const int ic = blk & 7;
  const int h = (blk >> 3) & 63;
  const int b = blk >> 9;
  const int i0 = ic << 6;
  const int t = threadIdx.x;
  const int w = t & 63;
  const int i4 = t >> 6;
  #pragma unroll
  for (int p = 0; p < 16; ++p) {
    const int ii = i4 + (p << 2);
    const float xv = x[((size_t)(b * CI + i0 + ii) * HH + h) * WW + w];
    const float sv = s[b * CI + i0 + ii];
    lds[w * 72 + ii] = f2bf(xv * sv);
  }
  // halo: side columns w=0,65 of this row
  const uint4 z4 = {0u, 0u, 0u, 0u};
  if (t < 16) {
    const int wside = (t < 8) ? 0 : 65;
    const int q = t & 7;
    *(uint4*)&xs[((size_t)(b * HP + h + 1) * WP + wside) * CI + i0 + (q << 3)] = z4;
  }
  // halo: full rows 0 and 65 (h==0 blocks only)
  if (h == 0) {
    for (int idx = t; idx < 2 * 66 * 8; idx += 256) {
      const int row = (idx < 528) ? 0 : 65;
      const int rem = (idx < 528) ? idx : idx - 528;
      const int wz = rem >> 3;
      const int q = rem & 7;
      *(uint4*)&xs[((size_t)(b * HP + row) * WP + wz) * CI + i0 + (q << 3)] = z4;
    }
  }
  __syncthreads();
  const int w2 = t >> 2;
  const int q = t & 3;
  const uint4* src = (const uint4*)&lds[w2 * 72 + (q << 4)];
  const uint4 v0 = src[0];
  const uint4 v1 = src[1];
  u16* dst = xs + ((size_t)(b * HP + h + 1) * WP + (w2 + 1)) * CI + i0 + (q << 4);
  *(uint4*)dst = v0;
  *((uint4*)dst + 1) = v1;
}

// ---------------------------------------------------------------------------
// implicit-GEMM conv, 256x256 deep-pipelined template (T2+T3+T4+T5):
// BM=256 (O), BN=256 (pixels = 4 rows x 64 w), BK=64, K = 9 taps x 512 = 72 tiles.
// 512 threads, 8 waves (2M x 4N), per-wave C = 128x64 (8m x 4n frags).
// LDS 128 KB: double-buffered A[256][64] + B[256][64] bf16, XOR slot swizzle.
// Stage split fine-grained: B(t+2) issued with P3's ds_reads (all lB reads of
// tile t are complete before every wave's P2 MFMA -> safe after P2 barrier);
// A(t+2) issued at P4 top. vmcnt(8) once per tile (t+2's 8 loads stay in
// flight; waits exactly for tile t+1).
// ---------------------------------------------------------------------------
__global__ __launch_bounds__(512, 2) void k_conv(
    const u16* __restrict__ xs, const u16* __restrict__ wb,
    const float* __restrict__ dmod, const float* __restrict__ bias,
    float* __restrict__ out)
{
  __shared__ __align__(16) u16 lA[2 * 16384];
  __shared__ __align__(16) u16 lB[2 * 16384];

  const int blk = blockIdx.x;
  const int nt = blk & 15;
  const int mt = (blk >> 4) & 1;
  const int b  = blk >> 5;
  const int ob = mt << 8;
  const int p0 = nt << 8;

  const int tid = threadIdx.x;
  const int wid = tid >> 6;
  const int lane = tid & 63;
  const int col = lane & 15;
  const int k8  = lane >> 4;
  const int wr  = wid >> 2;          // wave M index (0..1)
  const int wc  = wid & 3;           // wave N index (0..3)

  // staging lane geometry: gload16 stages 8 rows x 8 slots (1 KB), LDS linear.
  // source column pre-swizzled: lane l fetches slot (l&7)^(l>>3) of its row.
  const int lr = lane >> 3;
  const int ls = lane & 7;
  const int swz = ls ^ lr;

  u32 aoffs[4], boffs[4], ldst[4];
  #pragma unroll
  for (int g = 0; g < 4; ++g) {
    const int rg = (wid << 5) + (g << 3);        // row-group base 0..255
    aoffs[g] = (u32)((ob + rg + lr) * 4608 + (swz << 3));
    const int p = p0 + rg + lr;
    boffs[g] = (u32)(((b * HP + (p >> 6)) * WP + (p & 63)) * 512 + (swz << 3));
    ldst[g] = (u32)(rg << 6);
  }

  // ds_read swizzled slot offsets (elements): slot (kk*4+k8) ^ (row&7), row&7 == col&7
  const u32 sA0 = (u32)(((0 + k8) ^ (col & 7)) << 3);
  const u32 sA1 = (u32)(((4 + k8) ^ (col & 7)) << 3);
  const u32 aRead = (u32)((((wr << 7) + col) << 6));
  const u32 bRead = (u32)((((wc << 6) + col) << 6));

  floatx4 acc[8][4];
  #pragma unroll
  for (int m = 0; m < 8; ++m)
    #pragma unroll
    for (int n = 0; n < 4; ++n)
      acc[m][n] = (floatx4){0.f, 0.f, 0.f, 0.f};

  short8 a0[4][2], b0[2][2], b1[2][2];

#define STAGE_B(KC, C) do {                                                   \
    const int kc2_ = (KC);                                                    \
    const int tap_ = kc2_ >> 3;                                               \
    const int kh_ = tap_ / 3;                                                 \
    const int kw_ = tap_ - kh_ * 3;                                           \
    const u32 bt_ = (u32)(((kh_ * WP + kw_) << 9) + ((kc2_ & 7) << 6));       \
    _Pragma("unroll")                                                         \
    for (int g = 0; g < 4; ++g)                                               \
      gload16(xs + boffs[g] + bt_, &lB[((C) << 14) + ldst[g]]);               \
  } while (0)

#define STAGE_A(KC, C) do {                                                   \
    const u32 at_ = (u32)((KC) << 6);                                         \
    _Pragma("unroll")                                                         \
    for (int g = 0; g < 4; ++g)                                               \
      gload16(wb + aoffs[g] + at_, &lA[((C) << 14) + ldst[g]]);               \
  } while (0)

#define READ_A(PA, MH) do {                                                   \
    _Pragma("unroll")                                                         \
    for (int mq = 0; mq < 4; ++mq) {                                          \
      a0[mq][0] = *(const short8*)((PA) + (MH) * 4096 + mq * 1024 + sA0);     \
      a0[mq][1] = *(const short8*)((PA) + (MH) * 4096 + mq * 1024 + sA1);     \
    }                                                                         \
  } while (0)

#define READ_B(PB, NH, BV) do {                                               \
    _Pragma("unroll")                                                         \
    for (int nq = 0; nq < 2; ++nq) {                                          \
      BV[nq][0] = *(const short8*)((PB) + (NH) * 2048 + nq * 1024 + sA0);     \
      BV[nq][1] = *(const short8*)((PB) + (NH) * 2048 + nq * 1024 + sA1);     \
    }                                                                         \
  } while (0)

#define MFMA_Q(MH, NH, BV) do {                                               \
    _Pragma("unroll")                                                         \
    for (int kk = 0; kk < 2; ++kk)                                            \
      _Pragma("unroll")                                                       \
      for (int nq = 0; nq < 2; ++nq)                                          \
        _Pragma("unroll")                                                     \
        for (int mq = 0; mq < 4; ++mq)                                        \
          acc[(MH)*4+mq][(NH)*2+nq] = __builtin_amdgcn_mfma_f32_16x16x32_bf16(\
              a0[mq][kk], BV[nq][kk], acc[(MH)*4+mq][(NH)*2+nq], 0, 0, 0);    \
  } while (0)

#define BODY(T, DOSTAGE, WMODE) do {                                          \
    const int c_ = (T) & 1;                                                   \
    const u16* pA = lA + (c_ << 14) + aRead;                                  \
    const u16* pB = lB + (c_ << 14) + bRead;                                  \
    /* P1 */                                                                  \
    READ_A(pA, 0);                                                            \
    READ_B(pB, 0, b0);                                                        \
    __builtin_amdgcn_s_barrier();                                             \
    __builtin_amdgcn_s_setprio(1); MFMA_Q(0, 0, b0); __builtin_amdgcn_s_setprio(0); \
    __builtin_amdgcn_s_barrier();                                             \
    /* P2 */                                                                  \
    READ_B(pB, 1, b1);                                                        \
    __builtin_amdgcn_s_barrier();                                             \
    __builtin_amdgcn_s_setprio(1); MFMA_Q(0, 1, b1); __builtin_amdgcn_s_setprio(0); \
    __builtin_amdgcn_s_barrier();                                             \
    /* P3: stage B(t+2) interleaved with A1 reads (lB fully read by P2) */    \
    __builtin_amdgcn_sched_barrier(0);                                        \
    if (DOSTAGE) STAGE_B((T) + 2, c_);                                        \
    READ_A(pA, 1);                                                            \
    __builtin_amdgcn_s_barrier();                                             \
    __builtin_amdgcn_s_setprio(1); MFMA_Q(1, 1, b1); __builtin_amdgcn_s_setprio(0); \
    __builtin_amdgcn_s_barrier();                                             \
    /* P4: stage A(t+2), then last quadrant */                                \
    __builtin_amdgcn_sched_barrier(0);                                        \
    if (DOSTAGE) STAGE_A((T) + 2, c_);                                        \
    __builtin_amdgcn_s_setprio(1); MFMA_Q(1, 0, b0); __builtin_amdgcn_s_setprio(0); \
    if (WMODE == 1)      asm volatile("s_waitcnt vmcnt(8)" ::: "memory");     \
    else if (WMODE == 2) asm volatile("s_waitcnt vmcnt(0)" ::: "memory");     \
    __builtin_amdgcn_sched_barrier(0);                                        \
    if (WMODE != 0) __builtin_amdgcn_s_barrier();                             \
  } while (0)

  // prologue: stage tiles 0 and 1, wait for tile 0 (8 newer stay in flight)
  STAGE_B(0, 0); STAGE_A(0, 0);
  STAGE_B(1, 1); STAGE_A(1, 1);
  asm volatile("s_waitcnt vmcnt(8)" ::: "memory");
  __builtin_amdgcn_sched_barrier(0);
  __builtin_amdgcn_s_barrier();

  for (int t = 0; t < 70; ++t) BODY(t, 1, 1);
  BODY(70, 0, 2);
  BODY(71, 0, 0);

#undef STAGE_B
#undef STAGE_A
#undef READ_A
#undef READ_B
#undef MFMA_Q
#undef BODY

  // epilogue: out = acc * d[b,o] + bias[o]; C/D: col=lane&15, row=(lane>>4)*4+r
  #pragma unroll
  for (int m = 0; m < 8; ++m) {
    #pragma unroll
    for (int r = 0; r < 4; ++r) {
      const int o = ob + (wr << 7) + (m << 4) + (k8 << 2) + r;
      const float dm = dmod[b * CO + o];
      const float bs = bias[o];
      float* po = out + (((size_t)(b * CO + o)) << 12) + p0 + (wc << 6);
      #pragma unroll
      for (int n = 0; n < 4; ++n)
        po[(n << 4) + col] = acc[m][n][r] * dm + bs;
    }
  }
}

extern "C" void kernel_launch(void* const* d_in, const int* in_sizes, int n_in,
                              void* d_out, int out_size, void* d_ws, size_t ws_size,
                              hipStream_t stream) {
  const float* x    = (const float*)d_in[0];
  const float* y    = (const float*)d_in[1];
  const float* aw   = (const float*)d_in[2];
  const float* ab   = (const float*)d_in[3];
  const float* wt   = (const float*)d_in[4];
  const float* bias = (const float*)d_in[5];
  float* out = (float*)d_out;

  char* ws = (char*)d_ws;
  const size_t XS_BYTES = (size_t)NB * HP * WP * CI * 2;     // 35,684,352
  const size_t WB_BYTES = (size_t)CO * 9 * CI * 2;           //  4,718,592
  const size_t WS_BYTES = (size_t)CO * CI * 4;               //  1,048,576
  u16* xsb    = (u16*)ws;
  u16* wbuf   = (u16*)(ws + XS_BYTES);
  float* wsum = (float*)(ws + XS_BYTES + WB_BYTES);
  float* sbuf = (float*)(ws + XS_BYTES + WB_BYTES + WS_BYTES);
  float* dbuf = sbuf + NB * CI;

  k_style<<<dim3(1024), dim3(256), 0, stream>>>(y, aw, ab, sbuf);
  k_wprep<<<dim3(1024), dim3(256), 0, stream>>>(wt, wsum, wbuf);
  k_demod<<<dim3(1024), dim3(256), 0, stream>>>(wsum, sbuf, dbuf);
  k_xform<<<dim3(4096), dim3(256), 0, stream>>>(x, sbuf, xsb);
  k_conv <<<dim3(256), dim3(512), 0, stream>>>(xsb, wbuf, dbuf, bias, out);
}